// Round 7
// baseline (209.373 us; speedup 1.0000x reference)
//
#include <hip/hip_runtime.h>
#include <math.h>

#define BB 32
#define TT 1024
#define DD 256
#define PP 20
constexpr float EPS = 1e-12f;

typedef __attribute__((ext_vector_type(8))) short bf16x8;
typedef __attribute__((ext_vector_type(4))) float f32x4;

// round-to-nearest-even fp32 -> bf16
static __device__ __forceinline__ unsigned short f2bf(float f) {
    union { float f; unsigned int u; } c; c.f = f;
    const unsigned int u = c.u;
    return (unsigned short)((u + 0x7FFFu + ((u >> 16) & 1u)) >> 16);
}
#define BF2LO(u) __uint_as_float((u) << 16)
#define BF2HI(u) __uint_as_float((u) & 0xffff0000u)

// ---------------------------------------------------------------------------
// k_prep: per batch slab of 64 t-rows: row l2-norm, cvt bf16, and
//   outT[b][d][t]  <- normalized, TRANSPOSED (K-minor for MFMA)
//   outN[b][t][d]  <- RAW bf16 natural (k_hmean A; norm cancels in persp)
// ---------------------------------------------------------------------------
__global__ __launch_bounds__(256) void k_prep(const float* __restrict__ in,
                                              unsigned short* __restrict__ outT,
                                              unsigned short* __restrict__ outN) {
    __shared__ unsigned short Tls[DD][66];
    const int b = blockIdx.y;
    const int t0 = blockIdx.x * 64;
    const int wave = threadIdx.x >> 6;
    const int lane = threadIdx.x & 63;
    const float* src = in + (size_t)b * TT * DD;
    for (int pass = 0; pass < 16; ++pass) {
        const int tl = pass * 4 + wave;  // 0..63
        const int t = t0 + tl;
        const float4 v =
            *reinterpret_cast<const float4*>(&src[(size_t)t * DD + lane * 4]);
        float ss = v.x * v.x + v.y * v.y + v.z * v.z + v.w * v.w;
#pragma unroll
        for (int off = 32; off; off >>= 1) ss += __shfl_xor(ss, off);
        const float sc = 1.0f / sqrtf(fmaxf(ss, EPS));
        Tls[lane * 4 + 0][tl] = f2bf(v.x * sc);
        Tls[lane * 4 + 1][tl] = f2bf(v.y * sc);
        Tls[lane * 4 + 2][tl] = f2bf(v.z * sc);
        Tls[lane * 4 + 3][tl] = f2bf(v.w * sc);
        if (outN) {
            ushort4 r;
            r.x = f2bf(v.x); r.y = f2bf(v.y); r.z = f2bf(v.z); r.w = f2bf(v.w);
            *reinterpret_cast<ushort4*>(&outN[((size_t)b * TT + t) * DD + lane * 4]) = r;
        }
    }
    __syncthreads();
    const int d = threadIdx.x;
    unsigned short* dst = outT + ((size_t)b * DD + d) * TT + t0;
#pragma unroll
    for (int k = 0; k < 8; ++k) {
        unsigned short tmp[8];
#pragma unroll
        for (int j = 0; j < 8; ++j) tmp[j] = Tls[d][k * 8 + j];
        *reinterpret_cast<uint4*>(&dst[k * 8]) = *reinterpret_cast<const uint4*>(tmp);
    }
}

// ---------------------------------------------------------------------------
// k_gemm2<M,N,K,KS,OBF>: LDS-FREE wave-level GEMM.
// C[ks][b][m][n] = sum_{k in slice} A[b][m][k]*B[b][n][k], bf16 in.
// One wave owns a 32x32 output tile (2x2 16x16x32 frags). Fragments are
// loaded DIRECTLY global->VGPR (operands are K-minor; lane (fr,fc) reads
// row fr's bytes [k0+fc*16, +16) -> each frag-load = 16 rows x 64B, fully
// coalesced). No LDS, no barriers; 2-deep register double buffer.
// Cross-wave operand re-reads hit L1/L2 (per-batch working set <= 1 MB).
// Block = 4 waves = 4 consecutive jobs (nt fastest => shared A panel in L1).
// grid.x = BB*KS*(M/32)*(N/32)/4.
// ---------------------------------------------------------------------------
template <int M, int N, int K, int KS, bool OBF>
__global__ __launch_bounds__(256) void k_gemm2(const unsigned short* __restrict__ A,
                                               const unsigned short* __restrict__ B,
                                               void* __restrict__ Cv) {
    constexpr int MT = M / 32, NTL = N / 32, KSL = K / KS, NSTEP = KSL / 32;
    const int job = blockIdx.x * 4 + (threadIdx.x >> 6);
    const int lane = threadIdx.x & 63;
    const int nt = job % NTL;
    int r1 = job / NTL;
    const int mt = r1 % MT; r1 /= MT;
    const int ks = r1 % KS;
    const int b = r1 / KS;
    const int fr = lane & 15, fc = lane >> 4;
    const unsigned short* pA = A + ((size_t)b * M + mt * 32 + fr) * K + ks * KSL + fc * 8;
    const unsigned short* pB = B + ((size_t)b * N + nt * 32 + fr) * K + ks * KSL + fc * 8;

    uint4 ra[2][2], rb[2][2];
    f32x4 acc[2][2] = {};

#define LOADSTEP(buf, t)                                                      \
    {                                                                         \
        ra[buf][0] = *reinterpret_cast<const uint4*>(&pA[(t) * 32]);          \
        ra[buf][1] = *reinterpret_cast<const uint4*>(&pA[16 * K + (t) * 32]); \
        rb[buf][0] = *reinterpret_cast<const uint4*>(&pB[(t) * 32]);          \
        rb[buf][1] = *reinterpret_cast<const uint4*>(&pB[16 * K + (t) * 32]); \
    }
    LOADSTEP(0, 0)
    if (NSTEP > 1) LOADSTEP(1, 1)
#pragma unroll
    for (int t = 0; t < NSTEP; ++t) {
        const int cur = t & 1;  // static after full unroll
        const bf16x8 af0 = *reinterpret_cast<const bf16x8*>(&ra[cur][0]);
        const bf16x8 af1 = *reinterpret_cast<const bf16x8*>(&ra[cur][1]);
        const bf16x8 bf0 = *reinterpret_cast<const bf16x8*>(&rb[cur][0]);
        const bf16x8 bf1 = *reinterpret_cast<const bf16x8*>(&rb[cur][1]);
        acc[0][0] = __builtin_amdgcn_mfma_f32_16x16x32_bf16(af0, bf0, acc[0][0], 0, 0, 0);
        acc[0][1] = __builtin_amdgcn_mfma_f32_16x16x32_bf16(af0, bf1, acc[0][1], 0, 0, 0);
        acc[1][0] = __builtin_amdgcn_mfma_f32_16x16x32_bf16(af1, bf0, acc[1][0], 0, 0, 0);
        acc[1][1] = __builtin_amdgcn_mfma_f32_16x16x32_bf16(af1, bf1, acc[1][1], 0, 0, 0);
        if (t + 2 < NSTEP) LOADSTEP(cur, t + 2)
    }
#undef LOADSTEP
    // C/D layout: col = fr, row = fc*4 + r  (m89-verified)
    if constexpr (OBF) {
        unsigned short* C = (unsigned short*)Cv + (size_t)b * M * N;
#pragma unroll
        for (int i = 0; i < 2; ++i)
#pragma unroll
            for (int j = 0; j < 2; ++j)
#pragma unroll
                for (int r = 0; r < 4; ++r)
                    C[(size_t)(mt * 32 + i * 16 + fc * 4 + r) * N + nt * 32 + j * 16 + fr] =
                        f2bf(acc[i][j][r]);
    } else {
        float* C = (float*)Cv + ((size_t)ks * BB + b) * M * N;
#pragma unroll
        for (int i = 0; i < 2; ++i)
#pragma unroll
            for (int j = 0; j < 2; ++j)
#pragma unroll
                for (int r = 0; r < 4; ++r)
                    C[(size_t)(mt * 32 + i * 16 + fc * 4 + r) * N + nt * 32 + j * 16 + fr] =
                        acc[i][j][r];
    }
}

// ---------------------------------------------------------------------------
// k_alphanorm2: row = (b,e), 256 contiguous d. Sums optional split-K partial,
// l2-normalizes, writes bf16. One wave/row, 4 rows/block.
// ---------------------------------------------------------------------------
__global__ __launch_bounds__(256) void k_alphanorm2(const float* __restrict__ p0,
                                                    const float* __restrict__ p1,
                                                    unsigned short* __restrict__ dst) {
    const int wave = threadIdx.x >> 6;
    const int lane = threadIdx.x & 63;
    const size_t row = (size_t)blockIdx.x * 4 + wave;
    float4 v = reinterpret_cast<const float4*>(p0 + row * DD)[lane];
    if (p1) {
        const float4 w = reinterpret_cast<const float4*>(p1 + row * DD)[lane];
        v.x += w.x; v.y += w.y; v.z += w.z; v.w += w.w;
    }
    float s = v.x * v.x + v.y * v.y + v.z * v.z + v.w * v.w;
#pragma unroll
    for (int off = 32; off; off >>= 1) s += __shfl_xor(s, off);
    const float sc = 1.0f / sqrtf(fmaxf(s, EPS));
    ushort4 r;
    r.x = f2bf(v.x * sc); r.y = f2bf(v.y * sc);
    r.z = f2bf(v.z * sc); r.w = f2bf(v.w * sc);
    reinterpret_cast<ushort4*>(dst + row * DD)[lane] = r;
}

// ---------------------------------------------------------------------------
// k_persp2: persp via MFMA (num|sa|sh = (ah|aa|hh)·W2^T, K=256, N=32 pad).
// A-frags built in registers from fp32 a and bf16 hmean; B = packed w2
// fragments in LDS. num/sa/sh of one (row,p) land in SAME lane+reg ->
// lane-local ratio. No shfl. grid = BB*TT/64, 4 waves x 16 rows.
// ---------------------------------------------------------------------------
__global__ __launch_bounds__(256) void k_persp2(const float* __restrict__ inp_a,
                                                const unsigned short* __restrict__ hmeanb,
                                                const float* __restrict__ W,
                                                float* __restrict__ out) {
    __shared__ uint4 Bpk[8 * 2 * 64];  // [kstep][j][lane], 16 KB
    const int tid = threadIdx.x;
#pragma unroll
    for (int i = 0; i < 4; ++i) {
        const int ne = tid + i * 256;
        const int kstep = ne >> 7;
        const int j = (ne >> 6) & 1;
        const int ln = ne & 63;
        const int p = j * 16 + (ln & 15);
        const int k0 = kstep * 32 + (ln >> 4) * 8;
        unsigned short w8[8];
        if (p < PP) {
#pragma unroll
            for (int e = 0; e < 8; ++e) {
                const float w = W[p * DD + k0 + e];
                w8[e] = f2bf(w * w);
            }
        } else {
#pragma unroll
            for (int e = 0; e < 8; ++e) w8[e] = 0;
        }
        Bpk[ne] = *reinterpret_cast<const uint4*>(w8);
    }
    __syncthreads();

    const int wave = tid >> 6;
    const int lane = tid & 63;
    const int fr = lane & 15;
    const int fc = lane >> 4;
    const size_t row = (size_t)blockIdx.x * 64 + wave * 16 + fr;
    const float* pa = inp_a + row * DD + fc * 8;
    const unsigned short* ph = hmeanb + row * DD + fc * 8;
    const bf16x8* bp = reinterpret_cast<const bf16x8*>(Bpk);

    f32x4 acc[3][2] = {};
    float4 a0 = *reinterpret_cast<const float4*>(pa);
    float4 a1 = *reinterpret_cast<const float4*>(pa + 4);
    uint4 hq = *reinterpret_cast<const uint4*>(ph);

#pragma unroll
    for (int t = 0; t < 8; ++t) {
        float4 na0, na1;
        uint4 nhq;
        if (t < 7) {
            na0 = *reinterpret_cast<const float4*>(pa + (t + 1) * 32);
            na1 = *reinterpret_cast<const float4*>(pa + (t + 1) * 32 + 4);
            nhq = *reinterpret_cast<const uint4*>(ph + (t + 1) * 32);
        }
        const float av[8] = {a0.x, a0.y, a0.z, a0.w, a1.x, a1.y, a1.z, a1.w};
        const float hv[8] = {BF2LO(hq.x), BF2HI(hq.x), BF2LO(hq.y), BF2HI(hq.y),
                             BF2LO(hq.z), BF2HI(hq.z), BF2LO(hq.w), BF2HI(hq.w)};
        unsigned short ah[8], aa[8], hh[8];
#pragma unroll
        for (int e = 0; e < 8; ++e) {
            ah[e] = f2bf(av[e] * hv[e]);
            aa[e] = f2bf(av[e] * av[e]);
            hh[e] = f2bf(hv[e] * hv[e]);
        }
        const bf16x8 pf0 = *reinterpret_cast<const bf16x8*>(ah);
        const bf16x8 pf1 = *reinterpret_cast<const bf16x8*>(aa);
        const bf16x8 pf2 = *reinterpret_cast<const bf16x8*>(hh);
        const bf16x8 bf0 = bp[(t * 2 + 0) * 64 + lane];
        const bf16x8 bf1 = bp[(t * 2 + 1) * 64 + lane];
        acc[0][0] = __builtin_amdgcn_mfma_f32_16x16x32_bf16(pf0, bf0, acc[0][0], 0, 0, 0);
        acc[0][1] = __builtin_amdgcn_mfma_f32_16x16x32_bf16(pf0, bf1, acc[0][1], 0, 0, 0);
        acc[1][0] = __builtin_amdgcn_mfma_f32_16x16x32_bf16(pf1, bf0, acc[1][0], 0, 0, 0);
        acc[1][1] = __builtin_amdgcn_mfma_f32_16x16x32_bf16(pf1, bf1, acc[1][1], 0, 0, 0);
        acc[2][0] = __builtin_amdgcn_mfma_f32_16x16x32_bf16(pf2, bf0, acc[2][0], 0, 0, 0);
        acc[2][1] = __builtin_amdgcn_mfma_f32_16x16x32_bf16(pf2, bf1, acc[2][1], 0, 0, 0);
        a0 = na0; a1 = na1; hq = nhq;
    }

    const size_t rowbase = (size_t)blockIdx.x * 64 + wave * 16 + fc * 4;
#pragma unroll
    for (int j = 0; j < 2; ++j) {
        const int p = j * 16 + fr;
        if (p < PP) {
#pragma unroll
            for (int r = 0; r < 4; ++r) {
                const float num = acc[0][j][r];
                const float sa = sqrtf(fmaxf(acc[1][j][r], EPS));
                const float sh = sqrtf(fmaxf(acc[2][j][r], EPS));
                const float v = num / (sa * sh);
                const size_t o = (rowbase + r) * PP + p;
                out[o] = v;
                out[(size_t)BB * TT * PP + o] = v;
            }
        }
    }
}

// ---------------------------------------------------------------------------
extern "C" void kernel_launch(void* const* d_in, const int* in_sizes, int n_in,
                              void* d_out, int out_size, void* d_ws, size_t ws_size,
                              hipStream_t stream) {
    const float* inp_a = (const float*)d_in[0];
    const float* inp_b = (const float*)d_in[1];
    const float* W = (const float*)d_in[2];
    float* out = (float*)d_out;

    const size_t NTD = (size_t)BB * TT * DD;   // 8.39M elems
    const size_t NDD = (size_t)BB * DD * DD;   // 2.10M elems
    unsigned short* oaT = (unsigned short*)d_ws;          // [b][e][t] bf16
    unsigned short* obT = oaT + NTD;                      // [b][d][t] bf16
    unsigned short* hmeanb = oaT;                         // [b][t][e] bf16 (reuse)
    unsigned short* bnat = obT + NTD;                     // [b][t][d] bf16 raw
    float* aP0 = (float*)(bnat + NTD);                    // alphaT partial 0
    const bool SPLIT = ws_size >= (size_t)(NTD * 2 * 3 + NDD * 4 * 2 + NDD * 2);
    float* aP1 = SPLIT ? aP0 + NDD : nullptr;
    unsigned short* aTb = (unsigned short*)(aP0 + (SPLIT ? 2 * NDD : NDD));

    k_prep<<<dim3(TT / 64, BB), 256, 0, stream>>>(inp_a, oaT, nullptr);
    k_prep<<<dim3(TT / 64, BB), 256, 0, stream>>>(inp_b, obT, bnat);
    // alphaT[e][d] = sum_t oaT[e][t] * obT[d][t]
    if (SPLIT)
        k_gemm2<DD, DD, TT, 2, false>
            <<<BB * 2 * 8 * 8 / 4, 256, 0, stream>>>(oaT, obT, aP0);
    else
        k_gemm2<DD, DD, TT, 1, false>
            <<<BB * 1 * 8 * 8 / 4, 256, 0, stream>>>(oaT, obT, aP0);
    k_alphanorm2<<<BB * DD / 4, 256, 0, stream>>>(aP0, aP1, aTb);
    // hmean[t][e] = sum_d bnat[t][d] * aTb[e][d], bf16 out (scale cancels)
    k_gemm2<TT, DD, DD, 1, true>
        <<<BB * 1 * 32 * 8 / 4, 256, 0, stream>>>(bnat, aTb, (void*)hmeanb);
    k_persp2<<<BB * TT / 64, 256, 0, stream>>>(inp_a, hmeanb, W, out);
}

// Round 8
// 177.988 us; speedup vs baseline: 1.1763x; 1.1763x over previous
//
#include <hip/hip_runtime.h>
#include <math.h>

#define BB 32
#define TT 1024
#define DD 256
#define PP 20
constexpr float EPS = 1e-12f;

typedef __attribute__((ext_vector_type(8))) short bf16x8;
typedef __attribute__((ext_vector_type(4))) float f32x4;

// round-to-nearest-even fp32 -> bf16
static __device__ __forceinline__ unsigned short f2bf(float f) {
    union { float f; unsigned int u; } c; c.f = f;
    const unsigned int u = c.u;
    return (unsigned short)((u + 0x7FFFu + ((u >> 16) & 1u)) >> 16);
}
#define BF2LO(u) __uint_as_float((u) << 16)
#define BF2HI(u) __uint_as_float((u) & 0xffff0000u)

// ---------------------------------------------------------------------------
// k_prep: per batch slab of 64 t-rows: row l2-norm, cvt bf16, and
//   outT[b][d][t]  <- normalized, TRANSPOSED (K-minor for MFMA)
//   outN[b][t][d]  <- RAW bf16 natural (k_hmean A; norm cancels in persp)
// ---------------------------------------------------------------------------
__global__ __launch_bounds__(256) void k_prep(const float* __restrict__ in,
                                              unsigned short* __restrict__ outT,
                                              unsigned short* __restrict__ outN) {
    __shared__ unsigned short Tls[DD][66];
    const int b = blockIdx.y;
    const int t0 = blockIdx.x * 64;
    const int wave = threadIdx.x >> 6;
    const int lane = threadIdx.x & 63;
    const float* src = in + (size_t)b * TT * DD;
    for (int pass = 0; pass < 16; ++pass) {
        const int tl = pass * 4 + wave;  // 0..63
        const int t = t0 + tl;
        const float4 v =
            *reinterpret_cast<const float4*>(&src[(size_t)t * DD + lane * 4]);
        float ss = v.x * v.x + v.y * v.y + v.z * v.z + v.w * v.w;
#pragma unroll
        for (int off = 32; off; off >>= 1) ss += __shfl_xor(ss, off);
        const float sc = 1.0f / sqrtf(fmaxf(ss, EPS));
        Tls[lane * 4 + 0][tl] = f2bf(v.x * sc);
        Tls[lane * 4 + 1][tl] = f2bf(v.y * sc);
        Tls[lane * 4 + 2][tl] = f2bf(v.z * sc);
        Tls[lane * 4 + 3][tl] = f2bf(v.w * sc);
        if (outN) {
            ushort4 r;
            r.x = f2bf(v.x); r.y = f2bf(v.y); r.z = f2bf(v.z); r.w = f2bf(v.w);
            *reinterpret_cast<ushort4*>(&outN[((size_t)b * TT + t) * DD + lane * 4]) = r;
        }
    }
    __syncthreads();
    const int d = threadIdx.x;
    unsigned short* dst = outT + ((size_t)b * DD + d) * TT + t0;
#pragma unroll
    for (int k = 0; k < 8; ++k) {
        unsigned short tmp[8];
#pragma unroll
        for (int j = 0; j < 8; ++j) tmp[j] = Tls[d][k * 8 + j];
        *reinterpret_cast<uint4*>(&dst[k * 8]) = *reinterpret_cast<const uint4*>(tmp);
    }
}

// ---------------------------------------------------------------------------
// k_gemm<M,N,K,KS,OBF>: C[z][b][m][n] = sum_{k slice z} A[b][m][k]*B[b][n][k]
// bf16 in; f32 out (OBF=false) or bf16 out (OBF=true).
// 64x64 tile, 4 waves (2x2), 2x2 16x16x32 frags/wave, K-STEP 64
// (8 MFMA + 8 ds_read_b128 per phase, halves barrier count vs K-step 32).
// LDS rows padded to 72 ushorts: frag-read banks = 4*((fr+fc+..)%8) ->
// uniform 8 lanes per 16B slot = wave64 b128 minimum (conflict-free).
// 1-barrier reg-prefetch double buffer (load t+1 -> barrier -> compute t ->
// write t+1). grid = ((M/64)*(N/64), BB, KS).
// ---------------------------------------------------------------------------
template <int M, int N, int K, int KS, bool OBF>
__global__ __launch_bounds__(256) void k_gemm(const unsigned short* __restrict__ A,
                                              const unsigned short* __restrict__ B,
                                              void* __restrict__ Cv) {
    __shared__ unsigned short As[2][64][72];
    __shared__ unsigned short Bs[2][64][72];
    const int tid = threadIdx.x;
    const int b = blockIdx.y;
    constexpr int NTILES = N / 64;
    constexpr int KSL = K / KS;
    const int m0 = (blockIdx.x / NTILES) * 64;
    const int n0 = (blockIdx.x % NTILES) * 64;
    const int kbeg = blockIdx.z * KSL;
    const unsigned short* pA = A + (size_t)b * M * K + (size_t)m0 * K + kbeg;
    const unsigned short* pB = B + (size_t)b * N * K + (size_t)n0 * K + kbeg;
    const int srow = tid >> 2;          // staging row 0..63
    const int sk = (tid & 3) * 16;      // staging k-offset (bf16 units)
    const int wave = tid >> 6;
    const int lane = tid & 63;
    const int wm = (wave >> 1) * 32;
    const int wn = (wave & 1) * 32;
    const int fr = lane & 15;
    const int fc = lane >> 4;
    f32x4 acc[2][2] = {};
    uint4 ra0, ra1, rb0, rb1;

    ra0 = *reinterpret_cast<const uint4*>(&pA[(size_t)srow * K + sk]);
    ra1 = *reinterpret_cast<const uint4*>(&pA[(size_t)srow * K + sk + 8]);
    rb0 = *reinterpret_cast<const uint4*>(&pB[(size_t)srow * K + sk]);
    rb1 = *reinterpret_cast<const uint4*>(&pB[(size_t)srow * K + sk + 8]);
    *reinterpret_cast<uint4*>(&As[0][srow][sk]) = ra0;
    *reinterpret_cast<uint4*>(&As[0][srow][sk + 8]) = ra1;
    *reinterpret_cast<uint4*>(&Bs[0][srow][sk]) = rb0;
    *reinterpret_cast<uint4*>(&Bs[0][srow][sk + 8]) = rb1;

    constexpr int NT = KSL / 64;
    for (int t = 0; t < NT; ++t) {
        if (t + 1 < NT) {
            const int k0 = (t + 1) * 64;
            ra0 = *reinterpret_cast<const uint4*>(&pA[(size_t)srow * K + k0 + sk]);
            ra1 = *reinterpret_cast<const uint4*>(&pA[(size_t)srow * K + k0 + sk + 8]);
            rb0 = *reinterpret_cast<const uint4*>(&pB[(size_t)srow * K + k0 + sk]);
            rb1 = *reinterpret_cast<const uint4*>(&pB[(size_t)srow * K + k0 + sk + 8]);
        }
        __syncthreads();
        const int cur = t & 1;
#pragma unroll
        for (int kh = 0; kh < 2; ++kh) {
            bf16x8 af[2], bfr[2];
#pragma unroll
            for (int i = 0; i < 2; ++i) {
                af[i] = *reinterpret_cast<const bf16x8*>(
                    &As[cur][wm + i * 16 + fr][kh * 32 + fc * 8]);
                bfr[i] = *reinterpret_cast<const bf16x8*>(
                    &Bs[cur][wn + i * 16 + fr][kh * 32 + fc * 8]);
            }
#pragma unroll
            for (int i = 0; i < 2; ++i)
#pragma unroll
                for (int j = 0; j < 2; ++j)
                    acc[i][j] = __builtin_amdgcn_mfma_f32_16x16x32_bf16(
                        af[i], bfr[j], acc[i][j], 0, 0, 0);
        }
        if (t + 1 < NT) {
            const int nxt = (t + 1) & 1;
            *reinterpret_cast<uint4*>(&As[nxt][srow][sk]) = ra0;
            *reinterpret_cast<uint4*>(&As[nxt][srow][sk + 8]) = ra1;
            *reinterpret_cast<uint4*>(&Bs[nxt][srow][sk]) = rb0;
            *reinterpret_cast<uint4*>(&Bs[nxt][srow][sk + 8]) = rb1;
        }
    }
    // C/D layout: col = fr, row = fc*4 + r  (m89-verified)
    if constexpr (OBF) {
        unsigned short* C = (unsigned short*)Cv + (size_t)b * M * N;
#pragma unroll
        for (int i = 0; i < 2; ++i)
#pragma unroll
            for (int j = 0; j < 2; ++j)
#pragma unroll
                for (int r = 0; r < 4; ++r)
                    C[(size_t)(m0 + wm + i * 16 + fc * 4 + r) * N + n0 + wn + j * 16 + fr] =
                        f2bf(acc[i][j][r]);
    } else {
        float* C = (float*)Cv + ((size_t)blockIdx.z * BB + b) * M * N;
#pragma unroll
        for (int i = 0; i < 2; ++i)
#pragma unroll
            for (int j = 0; j < 2; ++j)
#pragma unroll
                for (int r = 0; r < 4; ++r)
                    C[(size_t)(m0 + wm + i * 16 + fc * 4 + r) * N + n0 + wn + j * 16 + fr] =
                        acc[i][j][r];
    }
}

// ---------------------------------------------------------------------------
// k_alphanorm2: row = (b,e), 256 contiguous d. Sums optional split-K partial,
// l2-normalizes, writes bf16. One wave/row, 4 rows/block.
// ---------------------------------------------------------------------------
__global__ __launch_bounds__(256) void k_alphanorm2(const float* __restrict__ p0,
                                                    const float* __restrict__ p1,
                                                    unsigned short* __restrict__ dst) {
    const int wave = threadIdx.x >> 6;
    const int lane = threadIdx.x & 63;
    const size_t row = (size_t)blockIdx.x * 4 + wave;
    float4 v = reinterpret_cast<const float4*>(p0 + row * DD)[lane];
    if (p1) {
        const float4 w = reinterpret_cast<const float4*>(p1 + row * DD)[lane];
        v.x += w.x; v.y += w.y; v.z += w.z; v.w += w.w;
    }
    float s = v.x * v.x + v.y * v.y + v.z * v.z + v.w * v.w;
#pragma unroll
    for (int off = 32; off; off >>= 1) s += __shfl_xor(s, off);
    const float sc = 1.0f / sqrtf(fmaxf(s, EPS));
    ushort4 r;
    r.x = f2bf(v.x * sc); r.y = f2bf(v.y * sc);
    r.z = f2bf(v.z * sc); r.w = f2bf(v.w * sc);
    reinterpret_cast<ushort4*>(dst + row * DD)[lane] = r;
}

// ---------------------------------------------------------------------------
// k_persp2: persp via MFMA (num|sa|sh = (ah|aa|hh)·W2^T, K=256, N=32 pad).
// A-frags built in registers from fp32 a and bf16 hmean; B = packed w2
// fragments in LDS. num/sa/sh of one (row,p) land in SAME lane+reg ->
// lane-local ratio. No shfl. grid = BB*TT/64, 4 waves x 16 rows.
// ---------------------------------------------------------------------------
__global__ __launch_bounds__(256) void k_persp2(const float* __restrict__ inp_a,
                                                const unsigned short* __restrict__ hmeanb,
                                                const float* __restrict__ W,
                                                float* __restrict__ out) {
    __shared__ uint4 Bpk[8 * 2 * 64];  // [kstep][j][lane], 16 KB
    const int tid = threadIdx.x;
#pragma unroll
    for (int i = 0; i < 4; ++i) {
        const int ne = tid + i * 256;
        const int kstep = ne >> 7;
        const int j = (ne >> 6) & 1;
        const int ln = ne & 63;
        const int p = j * 16 + (ln & 15);
        const int k0 = kstep * 32 + (ln >> 4) * 8;
        unsigned short w8[8];
        if (p < PP) {
#pragma unroll
            for (int e = 0; e < 8; ++e) {
                const float w = W[p * DD + k0 + e];
                w8[e] = f2bf(w * w);
            }
        } else {
#pragma unroll
            for (int e = 0; e < 8; ++e) w8[e] = 0;
        }
        Bpk[ne] = *reinterpret_cast<const uint4*>(w8);
    }
    __syncthreads();

    const int wave = tid >> 6;
    const int lane = tid & 63;
    const int fr = lane & 15;
    const int fc = lane >> 4;
    const size_t row = (size_t)blockIdx.x * 64 + wave * 16 + fr;
    const float* pa = inp_a + row * DD + fc * 8;
    const unsigned short* ph = hmeanb + row * DD + fc * 8;
    const bf16x8* bp = reinterpret_cast<const bf16x8*>(Bpk);

    f32x4 acc[3][2] = {};
    float4 a0 = *reinterpret_cast<const float4*>(pa);
    float4 a1 = *reinterpret_cast<const float4*>(pa + 4);
    uint4 hq = *reinterpret_cast<const uint4*>(ph);

#pragma unroll
    for (int t = 0; t < 8; ++t) {
        float4 na0, na1;
        uint4 nhq;
        if (t < 7) {
            na0 = *reinterpret_cast<const float4*>(pa + (t + 1) * 32);
            na1 = *reinterpret_cast<const float4*>(pa + (t + 1) * 32 + 4);
            nhq = *reinterpret_cast<const uint4*>(ph + (t + 1) * 32);
        }
        const float av[8] = {a0.x, a0.y, a0.z, a0.w, a1.x, a1.y, a1.z, a1.w};
        const float hv[8] = {BF2LO(hq.x), BF2HI(hq.x), BF2LO(hq.y), BF2HI(hq.y),
                             BF2LO(hq.z), BF2HI(hq.z), BF2LO(hq.w), BF2HI(hq.w)};
        unsigned short ah[8], aa[8], hh[8];
#pragma unroll
        for (int e = 0; e < 8; ++e) {
            ah[e] = f2bf(av[e] * hv[e]);
            aa[e] = f2bf(av[e] * av[e]);
            hh[e] = f2bf(hv[e] * hv[e]);
        }
        const bf16x8 pf0 = *reinterpret_cast<const bf16x8*>(ah);
        const bf16x8 pf1 = *reinterpret_cast<const bf16x8*>(aa);
        const bf16x8 pf2 = *reinterpret_cast<const bf16x8*>(hh);
        const bf16x8 bf0 = bp[(t * 2 + 0) * 64 + lane];
        const bf16x8 bf1 = bp[(t * 2 + 1) * 64 + lane];
        acc[0][0] = __builtin_amdgcn_mfma_f32_16x16x32_bf16(pf0, bf0, acc[0][0], 0, 0, 0);
        acc[0][1] = __builtin_amdgcn_mfma_f32_16x16x32_bf16(pf0, bf1, acc[0][1], 0, 0, 0);
        acc[1][0] = __builtin_amdgcn_mfma_f32_16x16x32_bf16(pf1, bf0, acc[1][0], 0, 0, 0);
        acc[1][1] = __builtin_amdgcn_mfma_f32_16x16x32_bf16(pf1, bf1, acc[1][1], 0, 0, 0);
        acc[2][0] = __builtin_amdgcn_mfma_f32_16x16x32_bf16(pf2, bf0, acc[2][0], 0, 0, 0);
        acc[2][1] = __builtin_amdgcn_mfma_f32_16x16x32_bf16(pf2, bf1, acc[2][1], 0, 0, 0);
        a0 = na0; a1 = na1; hq = nhq;
    }

    const size_t rowbase = (size_t)blockIdx.x * 64 + wave * 16 + fc * 4;
#pragma unroll
    for (int j = 0; j < 2; ++j) {
        const int p = j * 16 + fr;
        if (p < PP) {
#pragma unroll
            for (int r = 0; r < 4; ++r) {
                const float num = acc[0][j][r];
                const float sa = sqrtf(fmaxf(acc[1][j][r], EPS));
                const float sh = sqrtf(fmaxf(acc[2][j][r], EPS));
                const float v = num / (sa * sh);
                const size_t o = (rowbase + r) * PP + p;
                out[o] = v;
                out[(size_t)BB * TT * PP + o] = v;
            }
        }
    }
}

// ---------------------------------------------------------------------------
extern "C" void kernel_launch(void* const* d_in, const int* in_sizes, int n_in,
                              void* d_out, int out_size, void* d_ws, size_t ws_size,
                              hipStream_t stream) {
    const float* inp_a = (const float*)d_in[0];
    const float* inp_b = (const float*)d_in[1];
    const float* W = (const float*)d_in[2];
    float* out = (float*)d_out;

    const size_t NTD = (size_t)BB * TT * DD;   // 8.39M elems
    const size_t NDD = (size_t)BB * DD * DD;   // 2.10M elems
    unsigned short* oaT = (unsigned short*)d_ws;          // [b][e][t] bf16
    unsigned short* obT = oaT + NTD;                      // [b][d][t] bf16
    unsigned short* hmeanb = oaT;                         // [b][t][e] bf16 (reuse)
    unsigned short* bnat = obT + NTD;                     // [b][t][d] bf16 raw
    float* aP0 = (float*)(bnat + NTD);                    // alphaT partial 0
    const bool SPLIT = ws_size >= (size_t)(NTD * 2 * 3 + NDD * 4 * 2 + NDD * 2);
    float* aP1 = SPLIT ? aP0 + NDD : nullptr;
    unsigned short* aTb = (unsigned short*)(aP0 + (SPLIT ? 2 * NDD : NDD));

    k_prep<<<dim3(TT / 64, BB), 256, 0, stream>>>(inp_a, oaT, nullptr);
    k_prep<<<dim3(TT / 64, BB), 256, 0, stream>>>(inp_b, obT, bnat);
    // alphaT[e][d] = sum_t oaT[e][t] * obT[d][t]
    if (SPLIT)
        k_gemm<DD, DD, TT, 2, false>
            <<<dim3(16, BB, 2), 256, 0, stream>>>(oaT, obT, aP0);
    else
        k_gemm<DD, DD, TT, 1, false>
            <<<dim3(16, BB, 1), 256, 0, stream>>>(oaT, obT, aP0);
    k_alphanorm2<<<BB * DD / 4, 256, 0, stream>>>(aP0, aP1, aTb);
    // hmean[t][e] = sum_d bnat[t][d] * aTb[e][d], bf16 out (scale cancels)
    k_gemm<TT, DD, DD, 1, true>
        <<<dim3(64, BB, 1), 256, 0, stream>>>(bnat, aTb, (void*)hmeanb);
    k_persp2<<<BB * TT / 64, 256, 0, stream>>>(inp_a, hmeanb, W, out);
}